// Round 11
// baseline (77.492 us; speedup 1.0000x reference)
//
#include <hip/hip_runtime.h>
#include <math.h>

#define BB 64
#define NN 4096
#define DD 128
#define HH 256
#define MB 256                  // rows per fused block (8 waves x 2 tiles of 16)
#define NTHR 512                // 8 waves per block -> 2 blocks/CU = 16 waves/CU
#define NBLK (BB * NN / MB)     // 1024 blocks, 16 per batch
#define PPB 16                  // partials per batch
#define PSTRIDE 132             // per-block partial: 128 acc + m + z (+pad)

typedef __attribute__((ext_vector_type(8))) _Float16 f16x8;
typedef __attribute__((ext_vector_type(4))) float f32x4;

static __device__ __forceinline__ void gload_lds16(const void* g, void* l) {
    __builtin_amdgcn_global_load_lds(
        (const __attribute__((address_space(1))) unsigned int*)g,
        (__attribute__((address_space(3))) unsigned int*)l, 16, 0, 0);
}

// ---------------------------------------------------------------------------
// k_prep: W1 [128][256] fp32 -> Bws fp16, transposed per 16-col chunk,
// XOR-swizzled exactly as it will sit in LDS (linear global_load_lds copy).
// chunk region = 4096 B; elem (cl, k) at ((cl<<8)+(k<<1)) ^ ((cl&7)<<4).
// ---------------------------------------------------------------------------
__global__ __launch_bounds__(256) void k_prep(const float* __restrict__ W1,
                                              char* __restrict__ Bws) {
    const int k = blockIdx.x;       // 0..127
    const int c = threadIdx.x;      // 0..255
    const _Float16 h = (_Float16)W1[k * HH + c];
    const int chunk = c >> 4, cl = c & 15;
    const int off = ((cl << 8) + (k << 1)) ^ ((cl & 7) << 4);
    *(_Float16*)(Bws + chunk * 4096 + off) = h;
}

// ---------------------------------------------------------------------------
// k_fused (r6 structure, but 512-thread / 8-wave blocks):
//   scores (fp16 MFMA) -> block-local softmax -> weighted partial from the
//   SAME fp16 A fragments in registers. One pass over feats.
// r10 lesson: halving B-LDS didn't raise occupancy (VGPR granule) and the
// mid-loop stage stalled serially. Instead: 8 waves/block, single 64 KiB
// B-stage, 2 blocks/CU -> 16 waves/CU (2x r6's resident waves), af halved
// to 32 VGPR/thread. (512,4) pins the allocator to a 128-VGPR budget with
// ~30 regs of headroom (r8's spill came from a 64-reg budget, not the pin).
// ---------------------------------------------------------------------------
__global__ __launch_bounds__(NTHR, 4) void k_fused(const float* __restrict__ feats,
                                                   const char* __restrict__ Bws,
                                                   const float* __restrict__ b1,
                                                   const float* __restrict__ W2,
                                                   float* __restrict__ parts) {
    __shared__ char  Bl[65536];     // 16 chunks x 16 cols x 128 k, fp16 swizzled
    __shared__ float scores_l[256];
    __shared__ float ew[256];
    __shared__ float wacc[8][128];
    __shared__ float redm[8], redz[8];

    const int tid  = threadIdx.x;
    const int lane = tid & 63;
    const int wv   = tid >> 6;      // 0..7
    const int blk  = blockIdx.x;
    const int rl   = lane & 15;     // A row within tile / B col within chunk
    const int q    = lane >> 4;     // k-quarter (8 elems per K=32 step)

    // ---- stage all of B: 64 KiB = 8 iters x 512 threads x 16 B (linear)
    #pragma unroll
    for (int it = 0; it < 8; ++it)
        gload_lds16(Bws + it * 8192 + tid * 16, Bl + it * 8192 + tid * 16);

    // ---- A fragments direct from global, fp32->fp16 in regs.
    // lane (q,rl) holds rows r(t)=wv*32+t*16+rl, k = kk*32 + q*8 + e.
    f16x8 af[2][4];
    const float* fbase = feats + (size_t)blk * MB * DD;
    #pragma unroll
    for (int t = 0; t < 2; ++t) {
        const float* rp = fbase + (wv * 32 + t * 16 + rl) * DD + q * 8;
        #pragma unroll
        for (int kk = 0; kk < 4; ++kk) {
            float4 v0 = *(const float4*)(rp + kk * 32);
            float4 v1 = *(const float4*)(rp + kk * 32 + 4);
            f16x8 a;
            a[0] = (_Float16)v0.x; a[1] = (_Float16)v0.y;
            a[2] = (_Float16)v0.z; a[3] = (_Float16)v0.w;
            a[4] = (_Float16)v1.x; a[5] = (_Float16)v1.y;
            a[6] = (_Float16)v1.z; a[7] = (_Float16)v1.w;
            af[t][kk] = a;
        }
    }
    __syncthreads();                // B staged (vmcnt drained by barrier)

    float sp[2][4] = {{0,0,0,0},{0,0,0,0}};
    const int brow = rl << 8;
    const int bswz = (rl & 7) << 4;
    const int bq   = q << 4;

    #pragma unroll
    for (int chunk = 0; chunk < 16; ++chunk) {
        const float bbv = b1[chunk * 16 + rl];
        const float ww  = W2[chunk * 16 + rl];
        const char* cb = Bl + chunk * 4096;
        f32x4 acc0 = {0,0,0,0}, acc1 = {0,0,0,0};
        #pragma unroll
        for (int kk = 0; kk < 4; ++kk) {
            f16x8 bf = *(const f16x8*)(cb + (((brow + (kk << 6) + bq)) ^ bswz));
            acc0 = __builtin_amdgcn_mfma_f32_16x16x32_f16(af[0][kk], bf, acc0, 0, 0, 0);
            acc1 = __builtin_amdgcn_mfma_f32_16x16x32_f16(af[1][kk], bf, acc1, 0, 0, 0);
        }
        // fold relu + W2; D layout: col = rl, row = q*4 + j (within tile t)
        #pragma unroll
        for (int j = 0; j < 4; ++j) {
            sp[0][j] += fmaxf(acc0[j] + bbv, 0.f) * ww;
            sp[1][j] += fmaxf(acc1[j] + bbv, 0.f) * ww;
        }
    }

    // ---- scores: reduce over the 16 col-lanes (rl), publish to LDS
    #pragma unroll
    for (int m = 1; m < 16; m <<= 1)
        #pragma unroll
        for (int t = 0; t < 2; ++t)
            #pragma unroll
            for (int j = 0; j < 4; ++j)
                sp[t][j] += __shfl_xor(sp[t][j], m);
    if (rl == 0) {
        #pragma unroll
        for (int t = 0; t < 2; ++t)
            #pragma unroll
            for (int j = 0; j < 4; ++j)
                scores_l[wv * 32 + t * 16 + q * 4 + j] = sp[t][j];
    }
    __syncthreads();

    // ---- block-local softmax stats over the 256 rows (each score is read
    // by exactly two threads: tid and tid+256 -> z sums count it twice)
    const float s = scores_l[tid & 255];
    float mx = s;
    #pragma unroll
    for (int o = 1; o < 64; o <<= 1) mx = fmaxf(mx, __shfl_xor(mx, o));
    if (lane == 0) redm[wv] = mx;
    __syncthreads();
    mx = fmaxf(fmaxf(fmaxf(redm[0], redm[1]), fmaxf(redm[2], redm[3])),
               fmaxf(fmaxf(redm[4], redm[5]), fmaxf(redm[6], redm[7])));
    const float e = expf(s - mx);
    if (tid < 256) ew[tid] = e;
    float z = e;
    #pragma unroll
    for (int o = 1; o < 64; o <<= 1) z += __shfl_xor(z, o);
    if (lane == 0) redz[wv] = z;
    __syncthreads();
    const float zblk = 0.5f * (redz[0] + redz[1] + redz[2] + redz[3] +
                               redz[4] + redz[5] + redz[6] + redz[7]);

    // ---- weighted partial sum from the A fragments in registers
    const float w0 = ew[wv * 32 +  0 + rl];
    const float w1 = ew[wv * 32 + 16 + rl];
    float acc[4][8];
    #pragma unroll
    for (int kk = 0; kk < 4; ++kk)
        #pragma unroll
        for (int e8 = 0; e8 < 8; ++e8)
            acc[kk][e8] = w0 * (float)af[0][kk][e8] + w1 * (float)af[1][kk][e8];
    // reduce over the 16 row-lanes (rl) holding the same k-slice
    #pragma unroll
    for (int m = 1; m < 16; m <<= 1)
        #pragma unroll
        for (int kk = 0; kk < 4; ++kk)
            #pragma unroll
            for (int e8 = 0; e8 < 8; ++e8)
                acc[kk][e8] += __shfl_xor(acc[kk][e8], m);
    if (rl == 0) {
        #pragma unroll
        for (int kk = 0; kk < 4; ++kk)
            #pragma unroll
            for (int e8 = 0; e8 < 8; ++e8)
                wacc[wv][kk * 32 + q * 8 + e8] = acc[kk][e8];
    }
    __syncthreads();

    // ---- fold 8 waves, emit per-block partial (128 acc + m + z)
    if (tid < 128) {
        float p = wacc[0][tid] + wacc[1][tid] + wacc[2][tid] + wacc[3][tid]
                + wacc[4][tid] + wacc[5][tid] + wacc[6][tid] + wacc[7][tid];
        parts[blk * PSTRIDE + tid] = p;
    } else if (tid == 128) {
        parts[blk * PSTRIDE + 128] = mx;
        parts[blk * PSTRIDE + 129] = zblk;
    }
}

// ---------------------------------------------------------------------------
// k_out: combine 16 block-partials per batch with exact softmax rescaling.
// ---------------------------------------------------------------------------
__global__ __launch_bounds__(128) void k_out(const float* __restrict__ parts,
                                             float* __restrict__ out) {
    const int b = blockIdx.x;       // 0..63
    const int d = threadIdx.x;      // 0..127
    const float* pb = parts + (size_t)b * PPB * PSTRIDE;
    float M = -1e30f;
    #pragma unroll
    for (int i = 0; i < PPB; ++i) M = fmaxf(M, pb[i * PSTRIDE + 128]);
    float num = 0.f, den = 0.f;
    #pragma unroll
    for (int i = 0; i < PPB; ++i) {
        const float sc = expf(pb[i * PSTRIDE + 128] - M);
        num = fmaf(sc, pb[i * PSTRIDE + d], num);
        den = fmaf(sc, pb[i * PSTRIDE + 129], den);
    }
    out[b * DD + d] = num / den;
}

extern "C" void kernel_launch(void* const* d_in, const int* in_sizes, int n_in,
                              void* d_out, int out_size, void* d_ws, size_t ws_size,
                              hipStream_t stream) {
    const float* feats = (const float*)d_in[0];
    const float* W1    = (const float*)d_in[1];
    const float* b1    = (const float*)d_in[2];
    const float* W2    = (const float*)d_in[3];
    // d_in[4] = b2: constant shift before softmax -> no effect on output.
    float* out = (float*)d_out;

    char*  Bws   = (char*)d_ws;                     // 64 KiB: W1t fp16 swizzled
    float* parts = (float*)((char*)d_ws + 65536);   // 1024 * 132 floats

    hipLaunchKernelGGL(k_prep, dim3(DD), dim3(HH), 0, stream, W1, Bws);
    hipLaunchKernelGGL(k_fused, dim3(NBLK), dim3(NTHR), 0, stream,
                       feats, Bws, b1, W2, parts);
    hipLaunchKernelGGL(k_out, dim3(BB), dim3(128), 0, stream, parts, out);
}

// Round 12
// 63.044 us; speedup vs baseline: 1.2292x; 1.2292x over previous
//
#include <hip/hip_runtime.h>
#include <math.h>

#define BB 64
#define NN 4096
#define DD 128
#define HH 256
#define MB 256                  // rows per fused block (4 waves x 4 tiles of 16)
#define NBLK (BB * NN / MB)     // 1024 blocks, 16 per batch
#define PPB 16                  // partials per batch
#define PSTRIDE 132             // per-block partial: 128 acc + m + z (+pad)

typedef __attribute__((ext_vector_type(8))) _Float16 f16x8;
typedef __attribute__((ext_vector_type(4))) float f32x4;

static __device__ __forceinline__ void gload_lds16(const void* g, void* l) {
    __builtin_amdgcn_global_load_lds(
        (const __attribute__((address_space(1))) unsigned int*)g,
        (__attribute__((address_space(3))) unsigned int*)l, 16, 0, 0);
}

// ---------------------------------------------------------------------------
// k_prep: W1 [128][256] fp32 -> Bws fp16, transposed per 16-col chunk,
// XOR-swizzled exactly as it will sit in LDS (linear global_load_lds copy).
// chunk region = 4096 B; elem (cl, k) at ((cl<<8)+(k<<1)) ^ ((cl&7)<<4).
// ---------------------------------------------------------------------------
__global__ __launch_bounds__(256) void k_prep(const float* __restrict__ W1,
                                              char* __restrict__ Bws) {
    const int k = blockIdx.x;       // 0..127
    const int c = threadIdx.x;      // 0..255
    const _Float16 h = (_Float16)W1[k * HH + c];
    const int chunk = c >> 4, cl = c & 15;
    const int off = ((cl << 8) + (k << 1)) ^ ((cl & 7) << 4);
    *(_Float16*)(Bws + chunk * 4096 + off) = h;
}

// ---------------------------------------------------------------------------
// k_fused (r6 structure + latency batching):
//   scores (fp16 MFMA) -> block-local softmax -> weighted partial from the
//   SAME fp16 A fragments in registers. One pass over feats.
// r11/r8 lesson: __launch_bounds__ min-waves >= 4 forces a 64-VGPR budget
//   and 80-340 MB of scratch spill. Keep (256, 2).
// r12 changes vs r6: (a) A loads batched 8-wide per tile (4 latency
//   round-trips instead of 32); (b) b1/W2 preloaded to statically-indexed
//   registers (no global loads inside the MFMA loop).
// ---------------------------------------------------------------------------
__global__ __launch_bounds__(256, 2) void k_fused(const float* __restrict__ feats,
                                                  const char* __restrict__ Bws,
                                                  const float* __restrict__ b1,
                                                  const float* __restrict__ W2,
                                                  float* __restrict__ parts) {
    __shared__ char  Bl[65536];     // 16 chunks x 16 cols x 128 k, fp16 swizzled
    __shared__ float scores_l[256];
    __shared__ float ew[256];
    __shared__ float wacc[4][128];
    __shared__ float redm[4], redz[4];

    const int tid  = threadIdx.x;
    const int lane = tid & 63;
    const int wv   = tid >> 6;
    const int blk  = blockIdx.x;
    const int rl   = lane & 15;     // A row within tile / B col within chunk
    const int q    = lane >> 4;     // k-quarter (8 elems per K=32 step)

    // ---- stage all of B: 64 KiB = 16 iters x 256 threads x 16 B (linear)
    #pragma unroll
    for (int it = 0; it < 16; ++it)
        gload_lds16(Bws + it * 4096 + tid * 16, Bl + it * 4096 + tid * 16);

    // ---- preload bias/W2 for this lane's 16 chunk-columns (coalesced,
    // statically indexed by the unrolled chunk loop -> stays in VGPRs)
    float b1r[16], w2r[16];
    #pragma unroll
    for (int c = 0; c < 16; ++c) {
        b1r[c] = b1[c * 16 + rl];
        w2r[c] = W2[c * 16 + rl];
    }

    // ---- A fragments direct from global, fp32->fp16 in regs.
    // lane (q,rl) holds rows r(t)=wv*64+t*16+rl, k = kk*32 + q*8 + e.
    // All 8 loads of a tile issued back-to-back -> one vmcnt wait per tile.
    f16x8 af[4][4];
    const float* fbase = feats + (size_t)blk * MB * DD;
    #pragma unroll
    for (int t = 0; t < 4; ++t) {
        const float* rp = fbase + (wv * 64 + t * 16 + rl) * DD + q * 8;
        const float4 u0 = *(const float4*)(rp +   0);
        const float4 u1 = *(const float4*)(rp +   4);
        const float4 u2 = *(const float4*)(rp +  32);
        const float4 u3 = *(const float4*)(rp +  36);
        const float4 u4 = *(const float4*)(rp +  64);
        const float4 u5 = *(const float4*)(rp +  68);
        const float4 u6 = *(const float4*)(rp +  96);
        const float4 u7 = *(const float4*)(rp + 100);
#define CVT8(DST, A, B)                                                   \
        do { f16x8 _a;                                                    \
             _a[0] = (_Float16)(A).x; _a[1] = (_Float16)(A).y;            \
             _a[2] = (_Float16)(A).z; _a[3] = (_Float16)(A).w;            \
             _a[4] = (_Float16)(B).x; _a[5] = (_Float16)(B).y;            \
             _a[6] = (_Float16)(B).z; _a[7] = (_Float16)(B).w;            \
             DST = _a; } while (0)
        CVT8(af[t][0], u0, u1);
        CVT8(af[t][1], u2, u3);
        CVT8(af[t][2], u4, u5);
        CVT8(af[t][3], u6, u7);
#undef CVT8
    }
    __syncthreads();                // B staged (vmcnt drained by barrier)

    float sp[4][4] = {{0,0,0,0},{0,0,0,0},{0,0,0,0},{0,0,0,0}};
    const int brow = rl << 8;
    const int bswz = (rl & 7) << 4;
    const int bq   = q << 4;

    #pragma unroll
    for (int chunk = 0; chunk < 16; ++chunk) {
        const float bbv = b1r[chunk];
        const float ww  = w2r[chunk];
        const char* cb = Bl + chunk * 4096;
        f32x4 acc0 = {0,0,0,0}, acc1 = {0,0,0,0}, acc2 = {0,0,0,0}, acc3 = {0,0,0,0};
        #pragma unroll
        for (int kk = 0; kk < 4; ++kk) {
            f16x8 bf = *(const f16x8*)(cb + (((brow + (kk << 6) + bq)) ^ bswz));
            acc0 = __builtin_amdgcn_mfma_f32_16x16x32_f16(af[0][kk], bf, acc0, 0, 0, 0);
            acc1 = __builtin_amdgcn_mfma_f32_16x16x32_f16(af[1][kk], bf, acc1, 0, 0, 0);
            acc2 = __builtin_amdgcn_mfma_f32_16x16x32_f16(af[2][kk], bf, acc2, 0, 0, 0);
            acc3 = __builtin_amdgcn_mfma_f32_16x16x32_f16(af[3][kk], bf, acc3, 0, 0, 0);
        }
        // fold relu + W2; D layout: col = rl, row = q*4 + j (within tile t)
        #pragma unroll
        for (int j = 0; j < 4; ++j) {
            sp[0][j] += fmaxf(acc0[j] + bbv, 0.f) * ww;
            sp[1][j] += fmaxf(acc1[j] + bbv, 0.f) * ww;
            sp[2][j] += fmaxf(acc2[j] + bbv, 0.f) * ww;
            sp[3][j] += fmaxf(acc3[j] + bbv, 0.f) * ww;
        }
    }

    // ---- scores: reduce over the 16 col-lanes (rl), publish to LDS
    #pragma unroll
    for (int m = 1; m < 16; m <<= 1)
        #pragma unroll
        for (int t = 0; t < 4; ++t)
            #pragma unroll
            for (int j = 0; j < 4; ++j)
                sp[t][j] += __shfl_xor(sp[t][j], m);
    if (rl == 0) {
        #pragma unroll
        for (int t = 0; t < 4; ++t)
            #pragma unroll
            for (int j = 0; j < 4; ++j)
                scores_l[wv * 64 + t * 16 + q * 4 + j] = sp[t][j];
    }
    __syncthreads();

    // ---- block-local softmax stats over the 256 rows
    const float s = scores_l[tid];
    float mx = s;
    #pragma unroll
    for (int o = 1; o < 64; o <<= 1) mx = fmaxf(mx, __shfl_xor(mx, o));
    if (lane == 0) redm[wv] = mx;
    __syncthreads();
    mx = fmaxf(fmaxf(redm[0], redm[1]), fmaxf(redm[2], redm[3]));
    const float e = expf(s - mx);
    ew[tid] = e;
    float z = e;
    #pragma unroll
    for (int o = 1; o < 64; o <<= 1) z += __shfl_xor(z, o);
    if (lane == 0) redz[wv] = z;
    __syncthreads();
    const float zblk = redz[0] + redz[1] + redz[2] + redz[3];

    // ---- weighted partial sum from the A fragments in registers
    const float w0 = ew[wv * 64 +  0 + rl];
    const float w1 = ew[wv * 64 + 16 + rl];
    const float w2 = ew[wv * 64 + 32 + rl];
    const float w3 = ew[wv * 64 + 48 + rl];
    float acc[4][8];
    #pragma unroll
    for (int kk = 0; kk < 4; ++kk)
        #pragma unroll
        for (int e8 = 0; e8 < 8; ++e8)
            acc[kk][e8] = w0 * (float)af[0][kk][e8] + w1 * (float)af[1][kk][e8]
                        + w2 * (float)af[2][kk][e8] + w3 * (float)af[3][kk][e8];
    // reduce over the 16 row-lanes (rl) holding the same k-slice
    #pragma unroll
    for (int m = 1; m < 16; m <<= 1)
        #pragma unroll
        for (int kk = 0; kk < 4; ++kk)
            #pragma unroll
            for (int e8 = 0; e8 < 8; ++e8)
                acc[kk][e8] += __shfl_xor(acc[kk][e8], m);
    if (rl == 0) {
        #pragma unroll
        for (int kk = 0; kk < 4; ++kk)
            #pragma unroll
            for (int e8 = 0; e8 < 8; ++e8)
                wacc[wv][kk * 32 + q * 8 + e8] = acc[kk][e8];
    }
    __syncthreads();

    // ---- fold 4 waves, emit per-block partial (128 acc + m + z)
    if (tid < 128) {
        float p = wacc[0][tid] + wacc[1][tid] + wacc[2][tid] + wacc[3][tid];
        parts[blk * PSTRIDE + tid] = p;
    } else if (tid == 128) {
        parts[blk * PSTRIDE + 128] = mx;
        parts[blk * PSTRIDE + 129] = zblk;
    }
}

// ---------------------------------------------------------------------------
// k_out: combine 16 block-partials per batch with exact softmax rescaling.
// ---------------------------------------------------------------------------
__global__ __launch_bounds__(128) void k_out(const float* __restrict__ parts,
                                             float* __restrict__ out) {
    const int b = blockIdx.x;       // 0..63
    const int d = threadIdx.x;      // 0..127
    const float* pb = parts + (size_t)b * PPB * PSTRIDE;
    float M = -1e30f;
    #pragma unroll
    for (int i = 0; i < PPB; ++i) M = fmaxf(M, pb[i * PSTRIDE + 128]);
    float num = 0.f, den = 0.f;
    #pragma unroll
    for (int i = 0; i < PPB; ++i) {
        const float sc = expf(pb[i * PSTRIDE + 128] - M);
        num = fmaf(sc, pb[i * PSTRIDE + d], num);
        den = fmaf(sc, pb[i * PSTRIDE + 129], den);
    }
    out[b * DD + d] = num / den;
}

extern "C" void kernel_launch(void* const* d_in, const int* in_sizes, int n_in,
                              void* d_out, int out_size, void* d_ws, size_t ws_size,
                              hipStream_t stream) {
    const float* feats = (const float*)d_in[0];
    const float* W1    = (const float*)d_in[1];
    const float* b1    = (const float*)d_in[2];
    const float* W2    = (const float*)d_in[3];
    // d_in[4] = b2: constant shift before softmax -> no effect on output.
    float* out = (float*)d_out;

    char*  Bws   = (char*)d_ws;                     // 64 KiB: W1t fp16 swizzled
    float* parts = (float*)((char*)d_ws + 65536);   // 1024 * 132 floats

    hipLaunchKernelGGL(k_prep, dim3(DD), dim3(HH), 0, stream, W1, Bws);
    hipLaunchKernelGGL(k_fused, dim3(NBLK), dim3(256), 0, stream,
                       feats, Bws, b1, W2, parts);
    hipLaunchKernelGGL(k_out, dim3(BB), dim3(128), 0, stream, parts, out);
}